// Round 7
// baseline (290.820 us; speedup 1.0000x reference)
//
#include <hip/hip_runtime.h>
#include <hip/hip_bf16.h>
#include <math.h>

#define Bz 64
#define Sz 512
#define Hz 768
#define Nz 128
#define Ez 1024
#define GHz 128
#define FHz 256
#define Lz 2
#define BNz (Bz * Nz)          // 8192

typedef short bf16x8 __attribute__((ext_vector_type(8)));
typedef float f32x4  __attribute__((ext_vector_type(4)));
typedef unsigned short ushort;

__device__ inline ushort f2b(float f) {          // f32 -> bf16 bits, round-to-nearest-even
    union { float f; unsigned u; } v; v.f = f;
    unsigned r = (v.u + 0x7FFFu + ((v.u >> 16) & 1u)) >> 16;
    return (ushort)r;
}

// ============ convert W1, W2 to bf16 (one dispatch) ============
__global__ void k_convert(const float* __restrict__ W1, const float* __restrict__ W2,
                          ushort* __restrict__ W1b, ushort* __restrict__ W2b) {
    int i = blockIdx.x * 256 + threadIdx.x;      // 448 blocks
    if (i < Hz * GHz) W1b[i] = f2b(W1[i]);
    int j = i - Hz * GHz;
    if (j >= 0 && j < GHz * GHz) W2b[j] = f2b(W2[j]);
}

// ============ node gather: per (b,n) block; wave-synchronous gate; writes nf in bf16 ============
__global__ void k_node_gather(const float* __restrict__ lh, const int* __restrict__ submap,
                              const float* __restrict__ wr, const float* __restrict__ br,
                              ushort* __restrict__ nfb) {
    int n = blockIdx.x, b = blockIdx.y;
    int t = threadIdx.x;                  // 128 = 2 waves
    int lane = t & 63, wid = t >> 6;
    __shared__ int list[Sz];
    __shared__ int lcnt;
    __shared__ float partial[Hz];
    if (t == 0) lcnt = 0;
    __syncthreads();
    #pragma unroll
    for (int j = 0; j < 4; ++j) {
        int s = t + 128 * j;
        if (submap[b * Sz + s] == n) { int p = atomicAdd(&lcnt, 1); list[p] = s; }
    }
    __syncthreads();
    int cnt = lcnt;
    float brv = br[0];
    const float* wp = wr + lane * 12;
    float4 w0 = *(const float4*)&wp[0];
    float4 w1 = *(const float4*)&wp[4];
    float4 w2 = *(const float4*)&wp[8];
    float4 a0 = {0,0,0,0}, a1 = {0,0,0,0}, a2 = {0,0,0,0};
    for (int i = wid; i < cnt; i += 2) {
        const float* x = lh + (size_t)(b * Sz + list[i]) * Hz + lane * 12;
        float4 v0 = *(const float4*)&x[0];
        float4 v1 = *(const float4*)&x[4];
        float4 v2 = *(const float4*)&x[8];
        float p = v0.x*w0.x + v0.y*w0.y + v0.z*w0.z + v0.w*w0.w
                + v1.x*w1.x + v1.y*w1.y + v1.z*w1.z + v1.w*w1.w
                + v2.x*w2.x + v2.y*w2.y + v2.z*w2.z + v2.w*w2.w;
        #pragma unroll
        for (int off = 32; off > 0; off >>= 1) p += __shfl_down(p, off);
        float z = __shfl(p, 0) + brv;
        float g = 1.0f / (1.0f + __expf(-z));
        a0.x += g*v0.x; a0.y += g*v0.y; a0.z += g*v0.z; a0.w += g*v0.w;
        a1.x += g*v1.x; a1.y += g*v1.y; a1.z += g*v1.z; a1.w += g*v1.w;
        a2.x += g*v2.x; a2.y += g*v2.y; a2.z += g*v2.z; a2.w += g*v2.w;
    }
    if (wid == 1) {
        float* pp = partial + lane * 12;
        *(float4*)&pp[0] = a0; *(float4*)&pp[4] = a1; *(float4*)&pp[8] = a2;
    }
    __syncthreads();
    if (wid == 0) {
        float invc = 1.0f / fmaxf((float)cnt, 1.0f);
        const float* pp = partial + lane * 12;
        float4 p0 = *(const float4*)&pp[0];
        float4 p1 = *(const float4*)&pp[4];
        float4 p2 = *(const float4*)&pp[8];
        float o[12];
        o[0]=(a0.x+p0.x)*invc; o[1]=(a0.y+p0.y)*invc; o[2]=(a0.z+p0.z)*invc; o[3]=(a0.w+p0.w)*invc;
        o[4]=(a1.x+p1.x)*invc; o[5]=(a1.y+p1.y)*invc; o[6]=(a1.z+p1.z)*invc; o[7]=(a1.w+p1.w)*invc;
        o[8]=(a2.x+p2.x)*invc; o[9]=(a2.y+p2.y)*invc; o[10]=(a2.z+p2.z)*invc; o[11]=(a2.w+p2.w)*invc;
        unsigned* ob = (unsigned*)(nfb + (size_t)(b * Nz + n) * Hz + lane * 12);
        #pragma unroll
        for (int j = 0; j < 6; ++j)
            ob[j] = (unsigned)f2b(o[2*j]) | ((unsigned)f2b(o[2*j+1]) << 16);
    }
}

// ============ degree via per-batch LDS histogram; dinv = rsqrt(deg+1) — once per batch ============
__global__ void k_deg_dinv(const int* __restrict__ ei, float* __restrict__ dinv) {
    int b = blockIdx.x;
    int t = threadIdx.x;                  // 256
    __shared__ int hist[Nz];
    if (t < Nz) hist[t] = 0;
    __syncthreads();
    #pragma unroll
    for (int j = 0; j < 4; ++j) {
        int d = ei[b * 2 * Ez + Ez + t + 256 * j];
        atomicAdd(&hist[d], 1);
    }
    __syncthreads();
    if (t < Nz) dinv[b * Nz + t] = rsqrtf((float)hist[t] + 1.0f);
}

// ============ MFMA GEMM: C(BN x 128) = A_bf16(BN x K) @ W_bf16(K x 128), f32 out ============
// 128x128 tile, BK=64, register prefetch of next tile issued before the MFMA barrier.
// Layouts (m89/m91-verified): A-frag A[m=lane&15][k=q*8+j]; B-frag B[k=q*8+j][n=lane&15];
// C/D: row=q*4+reg, col=lane&15.
#define GSP 72                 // LDS row stride in bf16 (144 B, 16B-aligned)
template <int K>
__global__ void k_gemm_mfma(const ushort* __restrict__ A, const ushort* __restrict__ W,
                            float* __restrict__ C) {
    __shared__ __align__(16) ushort As[128 * GSP];   // [row][k]  (64-k slice)
    __shared__ __align__(16) ushort Bt[128 * GSP];   // [n][k]
    int row_base = blockIdx.x * 128;
    int tid = threadIdx.x;                // 256
    int w = tid >> 6, lane = tid & 63;
    int q = lane >> 4, l16 = lane & 15;
    f32x4 acc[2][8];
    #pragma unroll
    for (int rt = 0; rt < 2; ++rt)
        #pragma unroll
        for (int ct = 0; ct < 8; ++ct) acc[rt][ct] = (f32x4){0,0,0,0};

    int ar[4], aseg[4], bn[4], bks[4];
    #pragma unroll
    for (int rep = 0; rep < 4; ++rep) {
        int idx = tid + 256 * rep;
        ar[rep] = idx >> 3;  aseg[rep] = idx & 7;    // A: 128 rows x 8 segs of 8 k
        bn[rep] = idx & 127; bks[rep] = idx >> 7;    // B: 128 n x 8 ksegs of 8 k
    }
    uint4 apre[4], bpre[4];
    auto loadTiles = [&](int k0) {
        #pragma unroll
        for (int rep = 0; rep < 4; ++rep)
            apre[rep] = *(const uint4*)&A[(size_t)(row_base + ar[rep]) * K + k0 + aseg[rep] * 8];
        #pragma unroll
        for (int rep = 0; rep < 4; ++rep) {
            ushort u[8];
            #pragma unroll
            for (int j = 0; j < 8; ++j)
                u[j] = W[(size_t)(k0 + bks[rep] * 8 + j) * 128 + bn[rep]];
            bpre[rep].x = (unsigned)u[0] | ((unsigned)u[1] << 16);
            bpre[rep].y = (unsigned)u[2] | ((unsigned)u[3] << 16);
            bpre[rep].z = (unsigned)u[4] | ((unsigned)u[5] << 16);
            bpre[rep].w = (unsigned)u[6] | ((unsigned)u[7] << 16);
        }
    };

    loadTiles(0);
    for (int kk = 0; kk < K; kk += 64) {
        __syncthreads();                  // previous tile's consumers done
        #pragma unroll
        for (int rep = 0; rep < 4; ++rep) {
            *(uint4*)&As[ar[rep] * GSP + aseg[rep] * 8] = apre[rep];
            *(uint4*)&Bt[bn[rep] * GSP + bks[rep] * 8] = bpre[rep];
        }
        if (kk + 64 < K) loadTiles(kk + 64);   // global loads in flight during MFMAs
        __syncthreads();
        #pragma unroll
        for (int ks = 0; ks < 64; ks += 32) {
            bf16x8 af0 = *(const bf16x8*)&As[(w * 32 + l16) * GSP + ks + q * 8];
            bf16x8 af1 = *(const bf16x8*)&As[(w * 32 + 16 + l16) * GSP + ks + q * 8];
            #pragma unroll
            for (int ct = 0; ct < 8; ++ct) {
                bf16x8 bf = *(const bf16x8*)&Bt[(ct * 16 + l16) * GSP + ks + q * 8];
                acc[0][ct] = __builtin_amdgcn_mfma_f32_16x16x32_bf16(af0, bf, acc[0][ct], 0, 0, 0);
                acc[1][ct] = __builtin_amdgcn_mfma_f32_16x16x32_bf16(af1, bf, acc[1][ct], 0, 0, 0);
            }
        }
    }
    #pragma unroll
    for (int rt = 0; rt < 2; ++rt)
        #pragma unroll
        for (int ct = 0; ct < 8; ++ct)
            #pragma unroll
            for (int r = 0; r < 4; ++r)
                C[(size_t)(row_base + w * 32 + rt * 16 + q * 4 + r) * 128 + ct * 16 + l16] =
                    acc[rt][ct][r];
}

// ============ edge gather per (b,dst): dinv from global (LDS-cached row), precomputed norms ============
template <bool OUT_BF>
__global__ void k_edge_gather(const float* __restrict__ h, const int* __restrict__ ei,
                              const float* __restrict__ dinv, const float* __restrict__ bias,
                              float* __restrict__ outf, ushort* __restrict__ outb) {
    int d = blockIdx.x, b = blockIdx.y;
    int t = threadIdx.x;                  // 256
    __shared__ int list[Ez];
    __shared__ float nrm[Ez];
    __shared__ int lcnt;
    __shared__ float ldinv[Nz];
    __shared__ float accb[128];
    if (t == 0) lcnt = 0;
    if (t < Nz) ldinv[t] = dinv[b * Nz + t];
    __syncthreads();
    const int* srcp = ei + b * 2 * Ez;
    const int* dstp = srcp + Ez;
    #pragma unroll
    for (int j = 0; j < 4; ++j) {
        int e = t + 256 * j;
        if (dstp[e] == d) { int p = atomicAdd(&lcnt, 1); list[p] = e; }
    }
    __syncthreads();
    int cnt = lcnt;
    float dd = ldinv[d];
    for (int i = t; i < cnt; i += 256) {           // resolve src idx + norm up front
        int s = srcp[list[i]];
        list[i] = s;
        nrm[i] = ldinv[s] * dd;
    }
    __syncthreads();
    int col = t & 127, half = t >> 7;
    float acc = (half == 0) ? h[(size_t)(b * Nz + d) * GHz + col] * dd * dd : 0.0f;  // self loop
    for (int i = half; i < cnt; i += 2)
        acc += h[(size_t)(b * Nz + list[i]) * GHz + col] * nrm[i];
    if (half == 1) accb[col] = acc;
    __syncthreads();
    if (half == 0) {
        float v = fmaxf(acc + accb[col] + bias[col], 0.0f);
        if (OUT_BF) outb[(size_t)(b * Nz + d) * GHz + col] = f2b(v);
        else        outf[(size_t)(b * Nz + d) * GHz + col] = v;
    }
}

// ============ MLP stage 1 with fused pool: grid (8, B) = 512 blocks ============
// hmat[b][gcol] = relu([cls, mean_n(x2[b])] . Wf1[:,gcol] + bf1[gcol])
__global__ void k_mlp1(const float* __restrict__ lh, const float* __restrict__ x2,
                       const float* __restrict__ Wf1, const float* __restrict__ bf1,
                       float* __restrict__ hmat) {
    int b = blockIdx.y, cb = blockIdx.x;
    int t = threadIdx.x;                  // 256
    __shared__ float in[Hz + GHz];        // 896
    __shared__ float4 pbuf[8][32];
    __shared__ float red[8][32];
    for (int i = t; i < Hz; i += 256) in[i] = lh[(size_t)b * Sz * Hz + i];   // cls = s=0 row
    // pool: coalesced float4 sweep, 8 rows per pass x 16 passes
    int rl = t >> 5, c4 = t & 31;
    float4 a = {0, 0, 0, 0};
    for (int it = 0; it < 16; ++it) {
        float4 v = *(const float4*)&x2[(size_t)(b * Nz + it * 8 + rl) * GHz + c4 * 4];
        a.x += v.x; a.y += v.y; a.z += v.z; a.w += v.w;
    }
    pbuf[rl][c4] = a;
    __syncthreads();
    if (t < 32) {
        float4 s = {0, 0, 0, 0};
        #pragma unroll
        for (int r = 0; r < 8; ++r) {
            float4 v = pbuf[r][t];
            s.x += v.x; s.y += v.y; s.z += v.z; s.w += v.w;
        }
        in[Hz + t * 4 + 0] = s.x * (1.0f / Nz);
        in[Hz + t * 4 + 1] = s.y * (1.0f / Nz);
        in[Hz + t * 4 + 2] = s.z * (1.0f / Nz);
        in[Hz + t * 4 + 3] = s.w * (1.0f / Nz);
    }
    __syncthreads();
    // mlp1: 32 cols x 8 k-chunks of 112
    int col = t & 31, kc = t >> 5;
    int gcol = cb * 32 + col;
    float acc = 0.0f;
    int k1 = kc * 112 + 112;
    #pragma unroll 4
    for (int k = kc * 112; k < k1; ++k) acc += in[k] * Wf1[(size_t)k * FHz + gcol];
    red[kc][col] = acc;
    __syncthreads();
    if (kc == 0) {
        float s = bf1[gcol];
        #pragma unroll
        for (int r = 0; r < 8; ++r) s += red[r][col];
        hmat[b * FHz + gcol] = s > 0.0f ? s : 0.0f;
    }
}

// ============ MLP stage 2 ============
__global__ void k_mlp2(const float* __restrict__ hmat, const float* __restrict__ Wf2,
                       const float* __restrict__ bf2, float* __restrict__ out) {
    int b = blockIdx.x;
    int t = threadIdx.x;                  // 256
    float hv = hmat[b * FHz + t];
    __shared__ float red[256];
    for (int l = 0; l < Lz; ++l) {
        red[t] = hv * Wf2[t * Lz + l];
        __syncthreads();
        for (int s2 = 128; s2 > 0; s2 >>= 1) {
            if (t < s2) red[t] += red[t + s2];
            __syncthreads();
        }
        if (t == 0) out[b * Lz + l] = red[0] + bf2[l];
        __syncthreads();
    }
}

extern "C" void kernel_launch(void* const* d_in, const int* in_sizes, int n_in,
                              void* d_out, int out_size, void* d_ws, size_t ws_size,
                              hipStream_t stream) {
    const float* lh     = (const float*)d_in[0];
    const int*   submap = (const int*)d_in[1];
    const int*   ei     = (const int*)d_in[2];
    const float* wr  = (const float*)d_in[4];
    const float* br  = (const float*)d_in[5];
    const float* W1  = (const float*)d_in[6];
    const float* b1  = (const float*)d_in[7];
    const float* W2  = (const float*)d_in[8];
    const float* b2  = (const float*)d_in[9];
    const float* Wf1 = (const float*)d_in[10];
    const float* bf1 = (const float*)d_in[11];
    const float* Wf2 = (const float*)d_in[12];
    const float* bf2 = (const float*)d_in[13];
    float* out = (float*)d_out;

    // ---- workspace layout (16B-aligned chunks) ----
    char* p = (char*)d_ws;
    ushort* nfb  = (ushort*)p;  p += (size_t)BNz * Hz * 2;      // 12.6 MB bf16
    ushort* W1b  = (ushort*)p;  p += (size_t)Hz * GHz * 2;
    ushort* W2b  = (ushort*)p;  p += (size_t)GHz * GHz * 2;
    float*  dinv = (float*)p;   p += (size_t)BNz * 4;
    float*  h1   = (float*)p;   p += (size_t)BNz * GHz * 4;
    ushort* x1b  = (ushort*)p;  p += (size_t)BNz * GHz * 2;
    float*  h2   = (float*)p;   p += (size_t)BNz * GHz * 4;
    float*  x2   = (float*)p;   p += (size_t)BNz * GHz * 4;
    float*  hmat = (float*)p;   p += (size_t)Bz * FHz * 4;

    // no memsets, no global atomics; every buffer fully written before read
    k_convert<<<(Hz * GHz + GHz * GHz) / 256, 256, 0, stream>>>(W1, W2, W1b, W2b);
    k_node_gather<<<dim3(Nz, Bz), 128, 0, stream>>>(lh, submap, wr, br, nfb);
    k_deg_dinv<<<Bz, 256, 0, stream>>>(ei, dinv);

    k_gemm_mfma<Hz><<<BNz / 128, 256, 0, stream>>>(nfb, W1b, h1);
    k_edge_gather<true><<<dim3(Nz, Bz), 256, 0, stream>>>(h1, ei, dinv, b1, nullptr, x1b);

    k_gemm_mfma<GHz><<<BNz / 128, 256, 0, stream>>>(x1b, W2b, h2);
    k_edge_gather<false><<<dim3(Nz, Bz), 256, 0, stream>>>(h2, ei, dinv, b2, x2, nullptr);

    k_mlp1<<<dim3(8, Bz), 256, 0, stream>>>(lh, x2, Wf1, bf1, hmat);
    k_mlp2<<<Bz, 256, 0, stream>>>(hmat, Wf2, bf2, out);
}